// Round 5
// baseline (1102.418 us; speedup 1.0000x reference)
//
#include <hip/hip_runtime.h>

// Output = conv1x1(x, refine_w, refine_b). Everything else in the reference is
// dead code (`_dead` unused; x_back == x: permutation then its argsort-inverse).
//
// x: (8, 64, 256, 256) fp32, refine_w: (64, 64) [o-major], refine_b: (64,)
// out[b,o,h,w] = sum_c w[o,c] * x[b,c,h,w] + b[o]
//
// v6 = v5 + pinned occupancy. v5's counters (VGPR=40, VALU-busy 65us vs 27us
// FMA floor, WRITE +49MB) showed the allocator's occupancy heuristic at work:
// __launch_bounds__ only sets a MINIMUM waves/EU, so the allocator targeted
// more waves, squeezed to 40 VGPRs, and spilled -- first to AGPRs via
// v_accvgpr_write/read pairs (the 2.4x VALU inflation), then to scratch (the
// +49MB HBM writes). amdgpu_waves_per_eu(4,4) pins the range from BOTH sides:
// 4 waves/EU = 2 blocks/CU, hard 128-VGPR budget, everything fits in real
// VGPRs. Steady-state demand at the FMA floor: 2 blocks x 16KB per ~1.7us
// chunk phase = ~4.8 TB/s < 6.3 achievable -> FMA-issue-bound ~27us + edges.
// Accumulation order over c unchanged -> bit-identical results.

constexpr int  C      = 64;
constexpr long HW     = 65536;        // 256*256
constexpr long NPIX   = 8L * HW;      // 524288 pixels
constexpr int  WAVES  = 8;            // 512-thread block
constexpr int  OPT    = C / WAVES;    // 8 output channels per wave
constexpr int  PIXB   = 256;          // pixels per block tile (64 quads)
constexpr int  CCHUNK = 16;           // channels staged per chunk (16 KB)
constexpr int  NCHUNK = C / CCHUNK;   // 4 chunks
constexpr int  CPW    = CCHUNK / WAVES; // 2 channels staged per wave per chunk

typedef float f4 __attribute__((ext_vector_type(4)));

__device__ __forceinline__ void gload_lds16(const float* g, float* l)
{
    // one instr: 64 lanes x 16B contiguous -> LDS at (uniform l) + lane*16
    __builtin_amdgcn_global_load_lds(
        (const __attribute__((address_space(1))) unsigned int*)g,
        (__attribute__((address_space(3))) unsigned int*)l,
        16, 0, 0);
}

__global__
__attribute__((amdgpu_flat_work_group_size(512, 512), amdgpu_waves_per_eu(4, 4)))
void conv1x1_refine_kernel(
    const float* __restrict__ x,
    const float* __restrict__ w,     // (64,64) o-major
    const float* __restrict__ bias,  // (64,)
    float* __restrict__ out)
{
    __shared__ float lds[2][CCHUNK][PIXB];   // 2 x 16 KB

    const int t    = threadIdx.x;
    const int lane = t & 63;
    const int wv   = __builtin_amdgcn_readfirstlane(t >> 6);  // wave id -> SGPR

    const long pix0 = (long)blockIdx.x * PIXB;   // block's first pixel
    const long b    = pix0 >> 16;                // blocks never straddle a batch
    const long hw0  = pix0 & (HW - 1);

    const float* xb = x + b * ((long)C * HW) + hw0;
    float*       ob = out + b * ((long)C * HW) + (long)wv * OPT * HW + hw0;
    const float* wg = w + wv * OPT * C;          // this wave's 8 rows of w

    // wave wv stages chunk channels [wv*2, wv*2+1] (1 KB row each)
    auto stage = [&](int chunk, int buf) {
#pragma unroll
        for (int k = 0; k < CPW; ++k) {
            const int cc = wv * CPW + k;
            const int c  = chunk * CCHUNK + cc;
            gload_lds16(xb + (long)c * HW + (long)lane * 4, &lds[buf][cc][0]);
        }
    };

    f4 acc[OPT];
#pragma unroll
    for (int o = 0; o < OPT; ++o) {
        const float bv = bias[wv * OPT + o];     // uniform -> s_load
        acc[o] = (f4){bv, bv, bv, bv};
    }

    stage(0, 0);
    __syncthreads();                 // chunk 0 landed, all waves

#pragma unroll
    for (int cb = 0; cb < NCHUNK; ++cb) {
        // Prefetch next chunk into the other buffer; loads fly during compute,
        // the barrier's vmcnt drain lands after ~4096 cycles of FMA issue.
        if (cb + 1 < NCHUNK) stage(cb + 1, (cb + 1) & 1);

#pragma unroll
        for (int k = 0; k < CCHUNK; ++k) {
            const int c = cb * CCHUNK + k;
            const f4 xv = *reinterpret_cast<const f4*>(&lds[cb & 1][k][lane * 4]);
#pragma unroll
            for (int o = 0; o < OPT; ++o) {
                const float wvv = wg[o * C + c]; // uniform -> SGPR operand
                acc[o].x = fmaf(wvv, xv.x, acc[o].x);
                acc[o].y = fmaf(wvv, xv.y, acc[o].y);
                acc[o].z = fmaf(wvv, xv.z, acc[o].z);
                acc[o].w = fmaf(wvv, xv.w, acc[o].w);
            }
        }

        __syncthreads();   // next chunk landed + everyone done with this buf
    }

    // Streamed output, never re-read: nontemporal keeps x resident in LLC.
#pragma unroll
    for (int o = 0; o < OPT; ++o)
        __builtin_nontemporal_store(acc[o],
            reinterpret_cast<f4*>(ob + (long)o * HW + (long)lane * 4));
}

extern "C" void kernel_launch(void* const* d_in, const int* in_sizes, int n_in,
                              void* d_out, int out_size, void* d_ws, size_t ws_size,
                              hipStream_t stream)
{
    const float* x  = (const float*)d_in[0];   // x
    const float* rw = (const float*)d_in[11];  // refine_w
    const float* rb = (const float*)d_in[12];  // refine_b
    float* out = (float*)d_out;

    const int threads = 512;
    const int blocks  = (int)(NPIX / PIXB);    // 2048
    hipLaunchKernelGGL(conv1x1_refine_kernel, dim3(blocks), dim3(threads), 0, stream,
                       x, rw, rb, out);
}